// Round 6
// baseline (63.992 us; speedup 1.0000x reference)
//
#include <hip/hip_runtime.h>
#include <float.h>
#include <math.h>

#pragma clang fp contract(off)

#define R 8192
#define NCLS 80
#define SC 81          // scores row width (K+1)
#define TOPK_N 100
#define SCORE_THRESH 0.05f
#define NMS_THRESH 0.5f

// workspace layout (bytes)
#define BOXC_OFF   0            // float4[R]              131072
#define AREA_OFF   131072       // float[R] (<0 ⇒ row invalid)
#define CNT_OFF    163840       // uint (padded to 256)
#define ENT_OFF    164096       // u64 entries[NCLS*100] = 64000 -> ends 228096
#define SKEY_OFF   228352       // u64 skeys[NCLS][R] = 5242880 -> ends 5471232
#define CCNT_OFF   5471232      // int ccnt[NCLS] (padded to 5471552)
#define ST_OFF     5471552      // float scores_T[NCLS][R] = 2621440
#define NENT       (NCLS * TOPK_N)   // 8000

__device__ __forceinline__ bool finitef(float x) {
    return fabsf(x) <= FLT_MAX;   // false for NaN and +-inf
}

__device__ __forceinline__ float iou_f(float4 a, float aa, float4 b, float ab) {
    float ltx = fmaxf(a.x, b.x), lty = fmaxf(a.y, b.y);
    float rbx = fminf(a.z, b.z), rby = fminf(a.w, b.w);
    float iw = fmaxf(rbx - ltx, 0.f), ih = fmaxf(rby - lty, 0.f);
    float inter = iw * ih;
    float uni = aa + ab - inter + 1e-9f;
    return inter / uni;
}

// key packing: (score_bits << 13) | (8191 - r)  -> u64 desc == (score desc, r asc)
__device__ __forceinline__ unsigned long long pack_key(float sc, int r) {
    return ((unsigned long long)__float_as_uint(sc) << 13) |
           (unsigned long long)(8191 - r);
}

// ---------------- kernel A: coalesced prep (clip, validity, transpose) -------------
#define PREP_ROWS 32
#define PREP_THREADS 256

__global__ __launch_bounds__(PREP_THREADS) void prep_kernel(
    const float* __restrict__ boxes,
    const float* __restrict__ scores,
    const int* __restrict__ imh,
    const int* __restrict__ imw,
    float4* __restrict__ boxes_c,
    float* __restrict__ area,
    unsigned int* __restrict__ counter,
    unsigned long long* __restrict__ entries,
    float* __restrict__ scores_t,
    int do_t) {
    __shared__ float s_sc[PREP_ROWS * SC];   // 10368 B
    __shared__ int s_vld[PREP_ROWS];

    const int tid = threadIdx.x;
    const int blk = blockIdx.x;
    const int r0 = blk * PREP_ROWS;

    if (blk == 0 && tid == 0) *counter = 0u;
    {   // zero the 8000 entry slots across the first 32 blocks
        int i = blk * PREP_THREADS + tid;
        if (i < NENT) entries[i] = 0ull;
    }
    if (tid < PREP_ROWS) s_vld[tid] = 1;
    __syncthreads();

    // coalesced load of 32 rows x 81 scores; finiteness folded via LDS atomics
    const float* src = scores + (size_t)r0 * SC;
    for (int idx = tid; idx < PREP_ROWS * SC; idx += PREP_THREADS) {
        float v = src[idx];
        s_sc[idx] = v;
        if (!finitef(v)) atomicAnd(&s_vld[idx / SC], 0);
    }

    // boxes: 32 coalesced float4 loads
    float4 bc = make_float4(0.f, 0.f, 0.f, 0.f);
    float ar = 0.f;
    int bok = 1;
    if (tid < PREP_ROWS) {
        float4 b = ((const float4*)boxes)[r0 + tid];
        bok = finitef(b.x) && finitef(b.y) && finitef(b.z) && finitef(b.w);
        float w = (float)(*imw), h = (float)(*imh);
        bc.x = fminf(fmaxf(b.x, 0.f), w);
        bc.y = fminf(fmaxf(b.y, 0.f), h);
        bc.z = fminf(fmaxf(b.z, 0.f), w);
        bc.w = fminf(fmaxf(b.w, 0.f), h);
        ar = fmaxf(bc.z - bc.x, 0.f) * fmaxf(bc.w - bc.y, 0.f);
    }
    __syncthreads();
    if (tid < PREP_ROWS) {
        int v = s_vld[tid] && bok;
        s_vld[tid] = v;
        boxes_c[r0 + tid] = bc;
        area[r0 + tid] = v ? ar : -1.0f;   // sign marks invalid rows
    }
    __syncthreads();

    if (do_t) {
        // transposed store: scores_t[k][r0+rr], validity folded as -1
        for (int idx = tid; idx < NCLS * PREP_ROWS; idx += PREP_THREADS) {
            int k = idx >> 5;
            int rr = idx & 31;
            float v = s_sc[rr * SC + k];
            if (!s_vld[rr]) v = -1.0f;
            scores_t[(size_t)k * R + r0 + rr] = v;
        }
    }
}

// ---------------- kernel B1: per-class compact + rank-sort ----------------
#define NMS_THREADS 256

template <int U>
__device__ __forceinline__ void rank_sort_inplace(unsigned long long* s_key,
                                                  int cnt, int tid) {
    unsigned long long kv[U];
    int rk[U];
#pragma unroll
    for (int m = 0; m < U; ++m) {
        int i = tid + (m << 8);
        kv[m] = (i < cnt) ? s_key[i] : 0ull;
        rk[m] = 0;
    }
    if (tid < cnt) {
        int j = 0;
        for (; j + 2 <= cnt; j += 2) {
            unsigned long long a = s_key[j], b = s_key[j + 1];
#pragma unroll
            for (int m = 0; m < U; ++m)
                rk[m] += (int)(a > kv[m]) + (int)(b > kv[m]);
        }
        if (j < cnt) {
            unsigned long long a = s_key[j];
#pragma unroll
            for (int m = 0; m < U; ++m) rk[m] += (int)(a > kv[m]);
        }
    }
    __syncthreads();
#pragma unroll
    for (int m = 0; m < U; ++m) {
        int i = tid + (m << 8);
        if (i < cnt) s_key[rk[m]] = kv[m];   // ranks are a permutation (unique keys)
    }
}

__global__ __launch_bounds__(NMS_THREADS) void nms_sort_kernel(
    const float* __restrict__ scores,
    const float* __restrict__ scores_t,
    int use_t,
    const float* __restrict__ area,
    unsigned long long* __restrict__ skeys,
    int* __restrict__ ccnt) {
    __shared__ unsigned long long s_key[R];   // 64 KB
    __shared__ int s_cnt;

    const int tid = threadIdx.x;
    const int k = blockIdx.x;
    const int lane = tid & 63;

    if (tid == 0) s_cnt = 0;
    __syncthreads();

    if (use_t) {
        // ballot-append compaction (order irrelevant; rank-sort follows)
        const float4* col = (const float4*)(scores_t + (size_t)k * R);
        const unsigned long long ml = (1ull << lane) - 1ull;
        for (int i = tid; i < R / 4; i += NMS_THREADS) {
            float4 v = col[i];
            int r = i * 4;
            bool h0 = v.x > SCORE_THRESH, h1 = v.y > SCORE_THRESH;
            bool h2 = v.z > SCORE_THRESH, h3 = v.w > SCORE_THRESH;
            unsigned long long b0 = __ballot(h0), b1 = __ballot(h1);
            unsigned long long b2 = __ballot(h2), b3 = __ballot(h3);
            int n0 = __popcll(b0);
            int n01 = n0 + __popcll(b1);
            int n012 = n01 + __popcll(b2);
            int tot = n012 + __popcll(b3);
            int base = 0;
            if (lane == 0 && tot) base = atomicAdd(&s_cnt, tot);
            base = __shfl(base, 0);
            if (h0) s_key[base + __popcll(b0 & ml)] = pack_key(v.x, r);
            if (h1) s_key[base + n0 + __popcll(b1 & ml)] = pack_key(v.y, r + 1);
            if (h2) s_key[base + n01 + __popcll(b2 & ml)] = pack_key(v.z, r + 2);
            if (h3) s_key[base + n012 + __popcll(b3 & ml)] = pack_key(v.w, r + 3);
        }
    } else {
        for (int r = tid; r < R; r += NMS_THREADS) {
            float sc = scores[(size_t)r * SC + k];
            if (sc > SCORE_THRESH && area[r] >= 0.f) {
                int p = atomicAdd(&s_cnt, 1);
                s_key[p] = pack_key(sc, r);
            }
        }
    }
    __syncthreads();
    const int cnt = s_cnt;
    if (tid == 0) ccnt[k] = cnt;
    if (cnt == 0) return;

    if (cnt <= 256) {
        rank_sort_inplace<1>(s_key, cnt, tid);
    } else if (cnt <= 512) {
        rank_sort_inplace<2>(s_key, cnt, tid);
    } else if (cnt <= 1024) {
        rank_sort_inplace<4>(s_key, cnt, tid);
    } else if (cnt <= 2048) {
        rank_sort_inplace<8>(s_key, cnt, tid);
    } else {
        // bitonic fallback (not expected with this data distribution)
        int npad = 4096;
        while (npad < cnt) npad <<= 1;
        for (int i = cnt + tid; i < npad; i += NMS_THREADS) s_key[i] = 0ull;
        __syncthreads();
        for (int kk = 2; kk <= npad; kk <<= 1) {
            for (int j = kk >> 1; j > 0; j >>= 1) {
                for (int i = tid; i < npad; i += NMS_THREADS) {
                    int ixj = i ^ j;
                    if (ixj > i) {
                        unsigned long long a = s_key[i], b = s_key[ixj];
                        bool ascending = ((i & kk) == 0);
                        if ((b > a) == ascending) { s_key[i] = b; s_key[ixj] = a; }
                    }
                }
                __syncthreads();
            }
        }
    }
    __syncthreads();

    unsigned long long* dst = skeys + (size_t)k * R;
    for (int i = tid; i < cnt; i += NMS_THREADS) dst[i] = s_key[i];
}

// ---------------- kernel B2: per-class greedy NMS over sorted keys ----------------
#define KMAX 192   // kept-list cap: kept0<100 at chunk entry, +<=64 per chunk

__global__ __launch_bounds__(NMS_THREADS) void nms_greedy_kernel(
    const unsigned long long* __restrict__ skeys,
    const int* __restrict__ ccnt,
    const float4* __restrict__ boxes_c,
    const float* __restrict__ area,
    unsigned long long* __restrict__ entries,
    unsigned int* __restrict__ counter) {
    __shared__ float4 kb[KMAX];
    __shared__ float  ka[KMAX];
    __shared__ float4 s_cb[64];
    __shared__ float  s_car[64];
    __shared__ unsigned int s_part[4][64];
    __shared__ unsigned int s_sup1[4][64];
    __shared__ int s_kept;

    const int tid = threadIdx.x;
    const int k = blockIdx.x;
    const int lane = tid & 63;
    const int wv = tid >> 6;

    const int cnt = ccnt[k];
    if (cnt == 0) return;   // uniform
    if (tid == 0) s_kept = 0;
    __syncthreads();

    const unsigned long long* sk = skeys + (size_t)k * R;
    const int nchunks = (cnt + 63) >> 6;
    unsigned long long kv = 0ull;   // candidate key held by tid<64 across phases

    for (int c = 0; c < nchunks; ++c) {
        const int kept0 = s_kept;
        if (kept0 >= TOPK_N) break;       // uniform
        const int j = (c << 6) + lane;
        const bool incand = (j < cnt);

        if (tid < 64) {                    // stage chunk boxes into LDS
            float4 cb = make_float4(0.f, 0.f, 0.f, 0.f);
            float car = 0.f;
            kv = incand ? sk[j] : 0ull;
            if (incand) {
                int bidx = 8191 - (int)(kv & 8191ull);
                cb = boxes_c[bidx];
                car = area[bidx];
            }
            s_cb[lane] = cb;
            s_car[lane] = car;
        }
        __syncthreads();

        {   // parallel: kept-list test (slice over waves) + 64x64 adjacency partials
            float4 cb = s_cb[lane];
            float car = s_car[lane];
            unsigned int sup = 0u;
            for (int t = wv; t < kept0; t += 4)
                if (iou_f(cb, car, kb[t], ka[t]) > NMS_THRESH) sup = 1u;
            s_sup1[wv][lane] = sup;
            unsigned int pm = 0u;
            const int i0 = wv << 4;
#pragma unroll
            for (int ii = 0; ii < 16; ++ii) {
                int i = i0 + ii;
                if (i != lane && iou_f(cb, car, s_cb[i], s_car[i]) > NMS_THRESH)
                    pm |= 1u << ii;
            }
            s_part[wv][lane] = pm;
        }
        __syncthreads();

        if (tid < 64) {                    // wave 0: bitmask greedy resolve
            bool sup1 = (s_sup1[0][lane] | s_sup1[1][lane] |
                         s_sup1[2][lane] | s_sup1[3][lane]) != 0u;
            unsigned long long supmask =
                 (unsigned long long)s_part[0][lane]
               | ((unsigned long long)s_part[1][lane] << 16)
               | ((unsigned long long)s_part[2][lane] << 32)
               | ((unsigned long long)s_part[3][lane] << 48);
            bool alive0 = incand && !sup1;
            unsigned long long av = __ballot(alive0);
            unsigned long long kept = 0ull;
#pragma unroll
            for (int l = 0; l < 64; ++l) {
                unsigned long long m = __shfl(supmask, l);  // indep of `kept`
                if (((av >> l) & 1ull) && !(m & kept)) kept |= 1ull << l;
            }
            if ((kept >> lane) & 1ull) {
                int pos = kept0 + (int)__popcll(kept & ((1ull << lane) - 1ull));
                kb[pos] = s_cb[lane];
                ka[pos] = s_car[lane];
                if (pos < TOPK_N) {
                    int bidx = 8191 - (int)(kv & 8191ull);
                    unsigned int sb = (unsigned int)(kv >> 13);
                    entries[k * TOPK_N + pos] =
                        ((unsigned long long)(unsigned int)(k * R + bidx) << 32) |
                        (unsigned long long)sb;
                }
            }
            if (lane == 0) s_kept = kept0 + (int)__popcll(kept);
        }
        __syncthreads();
    }

    if (tid == 0) {
        int addv = s_kept < TOPK_N ? s_kept : TOPK_N;
        atomicAdd(counter, (unsigned int)addv);
    }
}

// ---------------- kernel C: radix-select top-100 of 8000 + output ----------------
#define TK_THREADS 256
#define TIECAP 512

__global__ __launch_bounds__(TK_THREADS) void topk_kernel(
    const unsigned long long* __restrict__ entries,
    const unsigned int* __restrict__ counter,
    const float4* __restrict__ boxes_c,
    float* __restrict__ out) {
    __shared__ unsigned int hist[4 * 1024];   // wave-private, 16 KB
    __shared__ unsigned int wt[4];
    __shared__ unsigned int s_binr[2];        // {bin, remaining rank}
    __shared__ unsigned int selk[TOPK_N];
    __shared__ int          selp[TOPK_N];
    __shared__ unsigned int fkey[TOPK_N];
    __shared__ int          fpos[TOPK_N];
    __shared__ int          tiepos[TIECAP];
    __shared__ unsigned int a_gt, a_tie;

    const int tid = threadIdx.x;
    const int wave = tid >> 6, lane = tid & 63;
    const unsigned int* e32 = (const unsigned int*)entries;

    unsigned int key[32];
#pragma unroll
    for (int i = 0; i < 32; ++i) {
        int idx = i * TK_THREADS + tid;
        key[i] = (idx < NENT) ? e32[2 * idx] : 0u;
    }
    const int M = (int)*counter;
    if (tid == 0) { a_gt = 0u; a_tie = 0u; }
    if (tid < TOPK_N) { fkey[tid] = 0u; fpos[tid] = 0; }

    unsigned int T = 0u;
    unsigned int needed_ties = 0u;
    if (M >= TOPK_N) {
        unsigned int r = TOPK_N;
        unsigned int P = 0x0Fu;       // keys are floats in (0.05,1]: bits 31..26
        int hi = 26;
        const int nbits_arr[3] = {8, 8, 10};
        for (int lvl = 0; lvl < 3; ++lvl) {
            const int nbits = nbits_arr[lvl];
            const int nb = 1 << nbits;
            const int sh = hi - nbits;
            for (int j = tid; j < 4 * 1024; j += TK_THREADS) hist[j] = 0u;
            __syncthreads();
            unsigned int* hw = &hist[wave * 1024];
#pragma unroll
            for (int i = 0; i < 32; ++i) {
                unsigned int kv = key[i];
                if ((kv >> hi) == P) atomicAdd(&hw[(kv >> sh) & (nb - 1)], 1u);
            }
            __syncthreads();
            const int G = nb >> 8;
            unsigned int g = 0u;
            for (int b = 0; b < G; ++b) {
                int bin = tid * G + b;
                g += hist[bin] + hist[1024 + bin] + hist[2048 + bin] + hist[3072 + bin];
            }
            unsigned int S = g;
            for (int off = 1; off < 64; off <<= 1) {
                unsigned int v = __shfl_down(S, off);
                if (lane + off < 64) S += v;
            }
            if (lane == 0) wt[wave] = S;
            __syncthreads();
            unsigned int above_w = 0u;
            for (int w2 = wave + 1; w2 < 4; ++w2) above_w += wt[w2];
            unsigned int Sown = S + above_w;
            unsigned int above = Sown - g;
            if (above < r && r <= Sown) {
                unsigned int cum = above;
                for (int b = G - 1; b >= 0; --b) {
                    int bin = tid * G + b;
                    unsigned int tb = hist[bin] + hist[1024 + bin] +
                                      hist[2048 + bin] + hist[3072 + bin];
                    cum += tb;
                    if (cum >= r) {
                        s_binr[0] = (unsigned int)bin;
                        s_binr[1] = r - (cum - tb);
                        break;
                    }
                }
            }
            __syncthreads();
            P = (P << nbits) | s_binr[0];
            r = s_binr[1];
            hi = sh;
            __syncthreads();
        }
        T = P;
        needed_ties = r;
    }
    __syncthreads();

    const unsigned int Teff = (M >= TOPK_N) ? T : 0u;
    if (M > 0) {
#pragma unroll
        for (int i = 0; i < 32; ++i) {
            unsigned int kv = key[i];
            int pos = i * TK_THREADS + tid;
            if (kv > Teff) {
                unsigned int p = atomicAdd(&a_gt, 1u);
                selk[p] = kv; selp[p] = pos;
            } else if (M >= TOPK_N && kv == Teff) {
                unsigned int q = atomicAdd(&a_tie, 1u);
                if (q < TIECAP) tiepos[q] = pos;
            }
        }
    }
    __syncthreads();
    const unsigned int ngt = a_gt;
    if (M >= TOPK_N && needed_ties > 0u) {
        unsigned int ntie = a_tie < TIECAP ? a_tie : TIECAP;
        for (unsigned int j = tid; j < ntie; j += TK_THREADS) {
            int pj = tiepos[j];
            unsigned int rnk = 0u;
            for (unsigned int j2 = 0; j2 < ntie; ++j2) rnk += (tiepos[j2] < pj);
            if (rnk < needed_ties) { selk[ngt + rnk] = T; selp[ngt + rnk] = pj; }
        }
    }
    __syncthreads();

    const int SELN = (M >= TOPK_N) ? TOPK_N : M;
    if (tid < SELN) {
        unsigned int kk = selk[tid];
        int pp = selp[tid];
        unsigned int rnk = 0u;
        for (int j = 0; j < SELN; ++j) {
            unsigned int kj = selk[j];
            int pj = selp[j];
            rnk += (kj > kk) || (kj == kk && pj < pp);
        }
        fkey[rnk] = kk;
        fpos[rnk] = pp;
    }
    __syncthreads();

    if (tid < TOPK_N) {
        bool dv = (tid < SELN);
        int pos = fpos[tid];
        float s = __uint_as_float(fkey[tid]);
        int flat = dv ? (int)e32[2 * pos + 1] : 0;
        int r = flat & (R - 1);
        int kc = flat >> 13;
        float4 bb = dv ? boxes_c[r] : make_float4(0.f, 0.f, 0.f, 0.f);
        out[tid * 4 + 0] = bb.x;
        out[tid * 4 + 1] = bb.y;
        out[tid * 4 + 2] = bb.z;
        out[tid * 4 + 3] = bb.w;
        out[400 + tid] = dv ? s : 0.f;
        out[500 + tid] = dv ? (float)kc : -1.f;
        out[600 + tid] = dv ? (float)r : -1.f;
    }
}

extern "C" void kernel_launch(void* const* d_in, const int* in_sizes, int n_in,
                              void* d_out, int out_size, void* d_ws, size_t ws_size,
                              hipStream_t stream) {
    const float* boxes  = (const float*)d_in[0];
    const float* scores = (const float*)d_in[1];
    const int*   imh    = (const int*)d_in[2];
    const int*   imw    = (const int*)d_in[3];

    char* ws = (char*)d_ws;
    float4*             boxes_c  = (float4*)(ws + BOXC_OFF);
    float*              area     = (float*)(ws + AREA_OFF);
    unsigned int*       counter  = (unsigned int*)(ws + CNT_OFF);
    unsigned long long* entries  = (unsigned long long*)(ws + ENT_OFF);
    unsigned long long* skeys    = (unsigned long long*)(ws + SKEY_OFF);
    int*                ccnt     = (int*)(ws + CCNT_OFF);
    float*              scores_t = (float*)(ws + ST_OFF);

    const size_t needed_t = (size_t)ST_OFF + (size_t)NCLS * R * sizeof(float);
    const int use_t = (ws_size >= needed_t) ? 1 : 0;

    prep_kernel<<<R / PREP_ROWS, PREP_THREADS, 0, stream>>>(
        boxes, scores, imh, imw, boxes_c, area, counter, entries, scores_t, use_t);
    nms_sort_kernel<<<NCLS, NMS_THREADS, 0, stream>>>(
        scores, scores_t, use_t, area, skeys, ccnt);
    nms_greedy_kernel<<<NCLS, NMS_THREADS, 0, stream>>>(
        skeys, ccnt, boxes_c, area, entries, counter);
    topk_kernel<<<1, TK_THREADS, 0, stream>>>(entries, counter, boxes_c,
                                              (float*)d_out);
}

// Round 7
// 63.921 us; speedup vs baseline: 1.0011x; 1.0011x over previous
//
#include <hip/hip_runtime.h>
#include <float.h>
#include <math.h>

#pragma clang fp contract(off)

#define R 8192
#define NCLS 80
#define SC 81          // scores row width (K+1)
#define TOPK_N 100
#define SCORE_THRESH 0.05f
#define NMS_THRESH 0.5f

// workspace layout (bytes)
#define BOXC_OFF   0            // float4[R]              131072
#define AREA_OFF   131072       // float[R] (<0 ⇒ row invalid)
#define ENT_OFF    163840       // u64 entries[NCLS*100] = 64000 -> ends 227840
#define CCNT_OFF   227840       // int ccnt[NCLS] -> 228160 (pad to 228352)
#define ST_OFF     228352       // float scores_T[NCLS][R] = 2621440
#define NENT       (NCLS * TOPK_N)   // 8000

__device__ __forceinline__ bool finitef(float x) {
    return fabsf(x) <= FLT_MAX;   // false for NaN and +-inf
}

__device__ __forceinline__ float iou_f(float4 a, float aa, float4 b, float ab) {
    float ltx = fmaxf(a.x, b.x), lty = fmaxf(a.y, b.y);
    float rbx = fminf(a.z, b.z), rby = fminf(a.w, b.w);
    float iw = fmaxf(rbx - ltx, 0.f), ih = fmaxf(rby - lty, 0.f);
    float inter = iw * ih;
    float uni = aa + ab - inter + 1e-9f;
    return inter / uni;
}

// key packing: (score_bits << 13) | (8191 - r)  -> u64 desc == (score desc, r asc)
__device__ __forceinline__ unsigned long long pack_key(float sc, int r) {
    return ((unsigned long long)__float_as_uint(sc) << 13) |
           (unsigned long long)(8191 - r);
}

// ---------------- kernel A: coalesced prep (clip, validity, transpose) -------------
#define PREP_ROWS 32
#define PREP_THREADS 256

__global__ __launch_bounds__(PREP_THREADS) void prep_kernel(
    const float* __restrict__ boxes,
    const float* __restrict__ scores,
    const int* __restrict__ imh,
    const int* __restrict__ imw,
    float4* __restrict__ boxes_c,
    float* __restrict__ area,
    unsigned long long* __restrict__ entries,
    float* __restrict__ scores_t,
    int do_t) {
    __shared__ float s_sc[PREP_ROWS * SC];   // 10368 B
    __shared__ int s_vld[PREP_ROWS];

    const int tid = threadIdx.x;
    const int blk = blockIdx.x;
    const int r0 = blk * PREP_ROWS;

    {   // zero the 8000 entry slots across the first 32 blocks
        int i = blk * PREP_THREADS + tid;
        if (i < NENT) entries[i] = 0ull;
    }
    if (tid < PREP_ROWS) s_vld[tid] = 1;
    __syncthreads();

    // coalesced load of 32 rows x 81 scores; finiteness folded via LDS atomics
    const float* src = scores + (size_t)r0 * SC;
    for (int idx = tid; idx < PREP_ROWS * SC; idx += PREP_THREADS) {
        float v = src[idx];
        s_sc[idx] = v;
        if (!finitef(v)) atomicAnd(&s_vld[idx / SC], 0);
    }

    // boxes: 32 coalesced float4 loads
    float4 bc = make_float4(0.f, 0.f, 0.f, 0.f);
    float ar = 0.f;
    int bok = 1;
    if (tid < PREP_ROWS) {
        float4 b = ((const float4*)boxes)[r0 + tid];
        bok = finitef(b.x) && finitef(b.y) && finitef(b.z) && finitef(b.w);
        float w = (float)(*imw), h = (float)(*imh);
        bc.x = fminf(fmaxf(b.x, 0.f), w);
        bc.y = fminf(fmaxf(b.y, 0.f), h);
        bc.z = fminf(fmaxf(b.z, 0.f), w);
        bc.w = fminf(fmaxf(b.w, 0.f), h);
        ar = fmaxf(bc.z - bc.x, 0.f) * fmaxf(bc.w - bc.y, 0.f);
    }
    __syncthreads();
    if (tid < PREP_ROWS) {
        int v = s_vld[tid] && bok;
        s_vld[tid] = v;
        boxes_c[r0 + tid] = bc;
        area[r0 + tid] = v ? ar : -1.0f;   // sign marks invalid rows
    }
    __syncthreads();

    if (do_t) {
        // transposed store: scores_t[k][r0+rr], validity folded as -1
        for (int idx = tid; idx < NCLS * PREP_ROWS; idx += PREP_THREADS) {
            int k = idx >> 5;
            int rr = idx & 31;
            float v = s_sc[rr * SC + k];
            if (!s_vld[rr]) v = -1.0f;
            scores_t[(size_t)k * R + r0 + rr] = v;
        }
    }
}

// ---------------- kernel B: per-class compact + sort + greedy NMS ----------------
#define NMS_THREADS 256
#define KMAX 192    // kept-list cap: kept0<100 at chunk entry, +<=64 per chunk
#define PF   512    // sorted candidates whose boxes are prefetched into LDS

template <int U>
__device__ __forceinline__ void rank_sort_inplace(unsigned long long* s_key,
                                                  int cnt, int tid) {
    unsigned long long kv[U];
    int rk[U];
#pragma unroll
    for (int m = 0; m < U; ++m) {
        int i = tid + (m << 8);
        kv[m] = (i < cnt) ? s_key[i] : 0ull;
        rk[m] = 0;
    }
    if (tid < cnt) {
        int j = 0;
        for (; j + 2 <= cnt; j += 2) {
            unsigned long long a = s_key[j], b = s_key[j + 1];
#pragma unroll
            for (int m = 0; m < U; ++m)
                rk[m] += (int)(a > kv[m]) + (int)(b > kv[m]);
        }
        if (j < cnt) {
            unsigned long long a = s_key[j];
#pragma unroll
            for (int m = 0; m < U; ++m) rk[m] += (int)(a > kv[m]);
        }
    }
    __syncthreads();
#pragma unroll
    for (int m = 0; m < U; ++m) {
        int i = tid + (m << 8);
        if (i < cnt) s_key[rk[m]] = kv[m];   // ranks are a permutation (unique keys)
    }
}

__global__ __launch_bounds__(NMS_THREADS) void nms_kernel(
    const float* __restrict__ scores,
    const float* __restrict__ scores_t,
    int use_t,
    const float4* __restrict__ boxes_c,
    const float* __restrict__ area,
    unsigned long long* __restrict__ entries,
    int* __restrict__ ccnt) {
    __shared__ unsigned long long s_key[R];   // 64 KB
    __shared__ float4 s_cb[PF];               // 8 KB  prefetched candidate boxes
    __shared__ float  s_ca[PF];               // 2 KB
    __shared__ float4 kb[KMAX];               // kept boxes
    __shared__ float  ka[KMAX];
    __shared__ float4 s_stg[64];              // fallback staging (chunks >= PF)
    __shared__ float  s_sca[64];
    __shared__ unsigned int s_part[4][64];
    __shared__ unsigned int s_sup1[4][64];
    __shared__ int s_cnt, s_kept;

    const int tid = threadIdx.x;
    const int k = blockIdx.x;
    const int lane = tid & 63;
    const int wv = tid >> 6;

    if (tid == 0) { s_cnt = 0; s_kept = 0; }
    __syncthreads();

    // ---- compaction ----
    if (use_t) {
        const float4* col = (const float4*)(scores_t + (size_t)k * R);
        const unsigned long long ml = (1ull << lane) - 1ull;
        for (int i = tid; i < R / 4; i += NMS_THREADS) {
            float4 v = col[i];
            int r = i * 4;
            bool h0 = v.x > SCORE_THRESH, h1 = v.y > SCORE_THRESH;
            bool h2 = v.z > SCORE_THRESH, h3 = v.w > SCORE_THRESH;
            unsigned long long b0 = __ballot(h0), b1 = __ballot(h1);
            unsigned long long b2 = __ballot(h2), b3 = __ballot(h3);
            int n0 = __popcll(b0);
            int n01 = n0 + __popcll(b1);
            int n012 = n01 + __popcll(b2);
            int tot = n012 + __popcll(b3);
            int base = 0;
            if (lane == 0 && tot) base = atomicAdd(&s_cnt, tot);
            base = __shfl(base, 0);
            if (h0) s_key[base + __popcll(b0 & ml)] = pack_key(v.x, r);
            if (h1) s_key[base + n0 + __popcll(b1 & ml)] = pack_key(v.y, r + 1);
            if (h2) s_key[base + n01 + __popcll(b2 & ml)] = pack_key(v.z, r + 2);
            if (h3) s_key[base + n012 + __popcll(b3 & ml)] = pack_key(v.w, r + 3);
        }
    } else {
        for (int r = tid; r < R; r += NMS_THREADS) {
            float sc = scores[(size_t)r * SC + k];
            if (sc > SCORE_THRESH && area[r] >= 0.f) {
                int p = atomicAdd(&s_cnt, 1);
                s_key[p] = pack_key(sc, r);
            }
        }
    }
    __syncthreads();
    const int cnt = s_cnt;
    if (cnt == 0) {
        if (tid == 0) ccnt[k] = 0;
        return;
    }

    // ---- sort (rank-sort tiers; bitonic fallback for cnt > 2048) ----
    if (cnt <= 256) {
        rank_sort_inplace<1>(s_key, cnt, tid);
    } else if (cnt <= 512) {
        rank_sort_inplace<2>(s_key, cnt, tid);
    } else if (cnt <= 1024) {
        rank_sort_inplace<4>(s_key, cnt, tid);
    } else if (cnt <= 2048) {
        rank_sort_inplace<8>(s_key, cnt, tid);
    } else {
        int npad = 4096;
        while (npad < cnt) npad <<= 1;
        for (int i = cnt + tid; i < npad; i += NMS_THREADS) s_key[i] = 0ull;
        __syncthreads();
        for (int kk = 2; kk <= npad; kk <<= 1) {
            for (int j = kk >> 1; j > 0; j >>= 1) {
                for (int i = tid; i < npad; i += NMS_THREADS) {
                    int ixj = i ^ j;
                    if (ixj > i) {
                        unsigned long long a = s_key[i], b = s_key[ixj];
                        bool ascending = ((i & kk) == 0);
                        if ((b > a) == ascending) { s_key[i] = b; s_key[ixj] = a; }
                    }
                }
                __syncthreads();
            }
        }
    }
    __syncthreads();

    // ---- prefetch boxes of first min(cnt,PF) sorted candidates into LDS ----
    const int pfn = cnt < PF ? cnt : PF;
    for (int i = tid; i < pfn; i += NMS_THREADS) {
        int b = 8191 - (int)(s_key[i] & 8191ull);
        s_cb[i] = boxes_c[b];
        s_ca[i] = area[b];
    }
    __syncthreads();

    // ---- greedy NMS: 2 barriers per 64-candidate chunk, LDS-only hot path ----
    const int nchunks = (cnt + 63) >> 6;
    for (int c = 0; c < nchunks; ++c) {
        const int kept0 = s_kept;
        if (kept0 >= TOPK_N) break;            // uniform
        const int jbase = c << 6;
        const int j = jbase + lane;
        const bool incand = (j < cnt);
        const bool pf = (jbase < PF);          // chunk fully within prefetch range

        if (!pf) {                             // cold path: stage via wave 0
            if (tid < 64) {
                float4 cb = make_float4(0.f, 0.f, 0.f, 0.f);
                float car = 0.f;
                if (incand) {
                    int b = 8191 - (int)(s_key[j] & 8191ull);
                    cb = boxes_c[b];
                    car = area[b];
                }
                s_stg[lane] = cb;
                s_sca[lane] = car;
            }
            __syncthreads();
        }

        float4 cb;
        float car;
        if (pf) {
            cb = incand ? s_cb[j] : make_float4(0.f, 0.f, 0.f, 0.f);
            car = incand ? s_ca[j] : 0.f;
        } else {
            cb = s_stg[lane];
            car = s_sca[lane];
        }

        {   // parallel: kept-list test (sliced over 4 waves) + 64x64 adjacency
            unsigned int sup = 0u;
            for (int t = wv; t < kept0; t += 4)
                if (iou_f(cb, car, kb[t], ka[t]) > NMS_THRESH) sup = 1u;
            s_sup1[wv][lane] = sup;
            unsigned int pm = 0u;
            const int i0 = wv << 4;
#pragma unroll
            for (int ii = 0; ii < 16; ++ii) {
                int i = i0 + ii;
                float4 ob = pf ? s_cb[jbase + i] : s_stg[i];
                float oa = pf ? s_ca[jbase + i] : s_sca[i];
                if (i != lane && iou_f(cb, car, ob, oa) > NMS_THRESH)
                    pm |= 1u << ii;
            }
            s_part[wv][lane] = pm;
        }
        __syncthreads();

        if (tid < 64) {                        // wave 0: bitmask greedy resolve
            bool sup1 = (s_sup1[0][lane] | s_sup1[1][lane] |
                         s_sup1[2][lane] | s_sup1[3][lane]) != 0u;
            unsigned long long supmask =
                 (unsigned long long)s_part[0][lane]
               | ((unsigned long long)s_part[1][lane] << 16)
               | ((unsigned long long)s_part[2][lane] << 32)
               | ((unsigned long long)s_part[3][lane] << 48);
            bool alive0 = incand && !sup1;
            unsigned long long av = __ballot(alive0);
            unsigned long long kept = 0ull;
#pragma unroll
            for (int l = 0; l < 64; ++l) {
                unsigned long long m = __shfl(supmask, l);  // indep of `kept`
                if (((av >> l) & 1ull) && !(m & kept)) kept |= 1ull << l;
            }
            if ((kept >> lane) & 1ull) {
                int pos = kept0 + (int)__popcll(kept & ((1ull << lane) - 1ull));
                kb[pos] = cb;
                ka[pos] = car;
                if (pos < TOPK_N) {
                    unsigned long long kv = s_key[j];
                    int bidx = 8191 - (int)(kv & 8191ull);
                    unsigned int sb = (unsigned int)(kv >> 13);
                    entries[k * TOPK_N + pos] =
                        ((unsigned long long)(unsigned int)(k * R + bidx) << 32) |
                        (unsigned long long)sb;
                }
            }
            if (lane == 0) s_kept = kept0 + (int)__popcll(kept);
        }
        __syncthreads();
    }

    if (tid == 0) {
        int kf = s_kept;
        ccnt[k] = kf < TOPK_N ? kf : TOPK_N;
    }
}

// ---------------- kernel C: radix-select top-100 of 8000 + output ----------------
#define TK_THREADS 256
#define TIECAP 512

__global__ __launch_bounds__(TK_THREADS) void topk_kernel(
    const unsigned long long* __restrict__ entries,
    const int* __restrict__ ccnt,
    const float4* __restrict__ boxes_c,
    float* __restrict__ out) {
    __shared__ unsigned int hist[4 * 1024];   // wave-private, 16 KB
    __shared__ unsigned int wt[4];
    __shared__ unsigned int s_binr[2];        // {bin, remaining rank}
    __shared__ unsigned int selk[TOPK_N];
    __shared__ int          selp[TOPK_N];
    __shared__ unsigned int fkey[TOPK_N];
    __shared__ int          fpos[TOPK_N];
    __shared__ int          tiepos[TIECAP];
    __shared__ unsigned int a_gt, a_tie;
    __shared__ int s_M;

    const int tid = threadIdx.x;
    const int wave = tid >> 6, lane = tid & 63;
    const unsigned int* e32 = (const unsigned int*)entries;

    unsigned int key[32];
#pragma unroll
    for (int i = 0; i < 32; ++i) {
        int idx = i * TK_THREADS + tid;
        key[i] = (idx < NENT) ? e32[2 * idx] : 0u;
    }
    if (tid == 0) { a_gt = 0u; a_tie = 0u; s_M = 0; }
    if (tid < TOPK_N) { fkey[tid] = 0u; fpos[tid] = 0; }
    __syncthreads();
    if (tid < NCLS) atomicAdd(&s_M, ccnt[tid]);   // ccnt already capped at 100
    __syncthreads();
    const int M = s_M;

    unsigned int T = 0u;
    unsigned int needed_ties = 0u;
    if (M >= TOPK_N) {
        unsigned int r = TOPK_N;
        unsigned int P = 0x0Fu;       // keys are floats in (0.05,1]: bits 31..26
        int hi = 26;
        const int nbits_arr[3] = {8, 8, 10};
        for (int lvl = 0; lvl < 3; ++lvl) {
            const int nbits = nbits_arr[lvl];
            const int nb = 1 << nbits;
            const int sh = hi - nbits;
            for (int j = tid; j < 4 * 1024; j += TK_THREADS) hist[j] = 0u;
            __syncthreads();
            unsigned int* hw = &hist[wave * 1024];
#pragma unroll
            for (int i = 0; i < 32; ++i) {
                unsigned int kv = key[i];
                if ((kv >> hi) == P) atomicAdd(&hw[(kv >> sh) & (nb - 1)], 1u);
            }
            __syncthreads();
            const int G = nb >> 8;
            unsigned int g = 0u;
            for (int b = 0; b < G; ++b) {
                int bin = tid * G + b;
                g += hist[bin] + hist[1024 + bin] + hist[2048 + bin] + hist[3072 + bin];
            }
            unsigned int S = g;
            for (int off = 1; off < 64; off <<= 1) {
                unsigned int v = __shfl_down(S, off);
                if (lane + off < 64) S += v;
            }
            if (lane == 0) wt[wave] = S;
            __syncthreads();
            unsigned int above_w = 0u;
            for (int w2 = wave + 1; w2 < 4; ++w2) above_w += wt[w2];
            unsigned int Sown = S + above_w;
            unsigned int above = Sown - g;
            if (above < r && r <= Sown) {
                unsigned int cum = above;
                for (int b = G - 1; b >= 0; --b) {
                    int bin = tid * G + b;
                    unsigned int tb = hist[bin] + hist[1024 + bin] +
                                      hist[2048 + bin] + hist[3072 + bin];
                    cum += tb;
                    if (cum >= r) {
                        s_binr[0] = (unsigned int)bin;
                        s_binr[1] = r - (cum - tb);
                        break;
                    }
                }
            }
            __syncthreads();
            P = (P << nbits) | s_binr[0];
            r = s_binr[1];
            hi = sh;
            __syncthreads();
        }
        T = P;
        needed_ties = r;
    }
    __syncthreads();

    const unsigned int Teff = (M >= TOPK_N) ? T : 0u;
    if (M > 0) {
#pragma unroll
        for (int i = 0; i < 32; ++i) {
            unsigned int kv = key[i];
            int pos = i * TK_THREADS + tid;
            if (kv > Teff) {
                unsigned int p = atomicAdd(&a_gt, 1u);
                selk[p] = kv; selp[p] = pos;
            } else if (M >= TOPK_N && kv == Teff) {
                unsigned int q = atomicAdd(&a_tie, 1u);
                if (q < TIECAP) tiepos[q] = pos;
            }
        }
    }
    __syncthreads();
    const unsigned int ngt = a_gt;
    if (M >= TOPK_N && needed_ties > 0u) {
        unsigned int ntie = a_tie < TIECAP ? a_tie : TIECAP;
        for (unsigned int j = tid; j < ntie; j += TK_THREADS) {
            int pj = tiepos[j];
            unsigned int rnk = 0u;
            for (unsigned int j2 = 0; j2 < ntie; ++j2) rnk += (tiepos[j2] < pj);
            if (rnk < needed_ties) { selk[ngt + rnk] = T; selp[ngt + rnk] = pj; }
        }
    }
    __syncthreads();

    const int SELN = (M >= TOPK_N) ? TOPK_N : M;
    if (tid < SELN) {
        unsigned int kk = selk[tid];
        int pp = selp[tid];
        unsigned int rnk = 0u;
        for (int j = 0; j < SELN; ++j) {
            unsigned int kj = selk[j];
            int pj = selp[j];
            rnk += (kj > kk) || (kj == kk && pj < pp);
        }
        fkey[rnk] = kk;
        fpos[rnk] = pp;
    }
    __syncthreads();

    if (tid < TOPK_N) {
        bool dv = (tid < SELN);
        int pos = fpos[tid];
        float s = __uint_as_float(fkey[tid]);
        int flat = dv ? (int)e32[2 * pos + 1] : 0;
        int r = flat & (R - 1);
        int kc = flat >> 13;
        float4 bb = dv ? boxes_c[r] : make_float4(0.f, 0.f, 0.f, 0.f);
        out[tid * 4 + 0] = bb.x;
        out[tid * 4 + 1] = bb.y;
        out[tid * 4 + 2] = bb.z;
        out[tid * 4 + 3] = bb.w;
        out[400 + tid] = dv ? s : 0.f;
        out[500 + tid] = dv ? (float)kc : -1.f;
        out[600 + tid] = dv ? (float)r : -1.f;
    }
}

extern "C" void kernel_launch(void* const* d_in, const int* in_sizes, int n_in,
                              void* d_out, int out_size, void* d_ws, size_t ws_size,
                              hipStream_t stream) {
    const float* boxes  = (const float*)d_in[0];
    const float* scores = (const float*)d_in[1];
    const int*   imh    = (const int*)d_in[2];
    const int*   imw    = (const int*)d_in[3];

    char* ws = (char*)d_ws;
    float4*             boxes_c  = (float4*)(ws + BOXC_OFF);
    float*              area     = (float*)(ws + AREA_OFF);
    unsigned long long* entries  = (unsigned long long*)(ws + ENT_OFF);
    int*                ccnt     = (int*)(ws + CCNT_OFF);
    float*              scores_t = (float*)(ws + ST_OFF);

    const size_t needed_t = (size_t)ST_OFF + (size_t)NCLS * R * sizeof(float);
    const int use_t = (ws_size >= needed_t) ? 1 : 0;

    prep_kernel<<<R / PREP_ROWS, PREP_THREADS, 0, stream>>>(
        boxes, scores, imh, imw, boxes_c, area, entries, scores_t, use_t);
    nms_kernel<<<NCLS, NMS_THREADS, 0, stream>>>(
        scores, scores_t, use_t, boxes_c, area, entries, ccnt);
    topk_kernel<<<1, TK_THREADS, 0, stream>>>(entries, ccnt, boxes_c,
                                              (float*)d_out);
}